// Round 10
// baseline (534.367 us; speedup 1.0000x reference)
//
#include <hip/hip_runtime.h>
#include <hip/hip_bf16.h>

// MLA prefill: B=2,S=2048,D=2048,H=16,DQK=128(=64 nope+64 rope),DV=128,QLR=1536,KVLR=1024
// INPUTS FP32; OUTPUT FP32. R19 (on R18=482.0us; R17=477.4):
//  (a) attn SPLIT-T: each (q-pair,h,b) tile-job split into 2 blocks covering
//      complementary t-ranges -> 1024 blocks = 4/CU (was 2/CU, grid-limited).
//      Total staging UNCHANGED (each t-tile staged once across halves).
//      Halves write normalized partial O (bf16) + (m,l) fp32 sidecar;
//      combine kernel merges exactly (weights l*2^(m-M); l=0 -> weight 0).
//  (b) T1 XCD swizzle REVERTED (R18: cost ~5us; operands L3-fit -> no gain).
//  Kept: R13 staging, swapped QK^T, in-reg P (R18), T13 defer-rescale,
//        fused A-proj, gemm 2-phase dbuf.
//  BANNED: divergent-base global_load_lds. ABANDONED: T14 reg-carriers.
// No __expf (container-killer). No INFINITY (finite-math safe).
//
// Workspace map (80MB proven writable in R1):
//   kv2  @ 0         (4096x3072 bf16, 25.2MB)  live: kv2-gemm .. attn
//   kpe  @ 25165824  (4096x64  bf16,  0.5MB)   live: rope_k .. attn
//   cq   @ 25690112  (4096x2624 bf16, 21.5MB)  cols 0-1087=kvb, 1088-2623=qa
//        after q_b gemm: pO0 (4096x2048 bf16, 16.8MB) + ml sidecar @+16.8MB
//        (2x2x2048x16 float2 = 2MB); combine writes final attno in-place.
//   xb   @ 47185920  (4096x2048 bf16, 16.8MB)  cvt..fused-gemm; then pO1.
//   wslot@ 63963136  (11.0MB weight slot: wkv_a+wq_a fused / wkv_b / wq_b / wo)
//   qbuf (4096x2048 bf16) lives in d_out until out-gemm.

using bf16 = __hip_bfloat16;
typedef __attribute__((ext_vector_type(8))) short bf16x8;
typedef __attribute__((ext_vector_type(4))) float f32x4;

#define S_ 2048
#define NEG_BIG (-1e30f)
#define LOG2E 1.4426950408889634f

static __device__ __forceinline__ f32x4 mfma16(bf16x8 a, bf16x8 b, f32x4 c) {
    return __builtin_amdgcn_mfma_f32_16x16x32_bf16(a, b, c, 0, 0, 0);
}

// async global->LDS, 16B per lane. LDS dest must be lane-linear per wave;
// global src must be a single affine base (no divergent base select!).
static __device__ __forceinline__ void gload_lds16(const bf16* g, bf16* l) {
    __builtin_amdgcn_global_load_lds(
        (const __attribute__((address_space(1))) void*)g,
        (__attribute__((address_space(3))) void*)l, 16, 0, 0);
}

// ---------------------------------------------------------------------------
// fp32 -> bf16 bulk convert, 4 elems/thread.
// ---------------------------------------------------------------------------
__global__ __launch_bounds__(256) void f2b(const float* __restrict__ src,
                                           bf16* __restrict__ dst, int n4) {
    int i = blockIdx.x * 256 + threadIdx.x;
    if (i < n4) {
        float4 v = ((const float4*)src)[i];
        alignas(8) bf16 t[4];
        t[0] = (bf16)v.x; t[1] = (bf16)v.y; t[2] = (bf16)v.z; t[3] = (bf16)v.w;
        ((uint2*)dst)[i] = *(const uint2*)t;
    }
}

// ---------------------------------------------------------------------------
// GEMM: C[M,N] = A[M,K] @ B[N,K]^T. 128x128 tile, BK=32, 256 thr, bf16 in.
// Double-buffered staging via global_load_lds; swizzle on GLOBAL src address,
// LDS linear. One __syncthreads per K-step (implicit vmcnt+lgkm drain).
// NOTE: no N-guard in staging -- caller guarantees B rows up to grid.y*128
// readable (ragged N reads junk rows; cols>=N never stored).
// ---------------------------------------------------------------------------
template <bool C_F32>
__global__ __launch_bounds__(256) void gemm_bt(const bf16* __restrict__ A,
                                               const bf16* __restrict__ Bw,
                                               void* __restrict__ Cv,
                                               int M, int N, int K,
                                               int lda, int ldb, int ldc) {
    __shared__ bf16 As[2][128 * 32];
    __shared__ bf16 Bs[2][128 * 32];
    const int tid = threadIdx.x;
    const int m0 = blockIdx.x * 128;
    const int n0 = blockIdx.y * 128;
    const int w = tid >> 6, lane = tid & 63, quad = lane >> 4, l15 = lane & 15;
    const int wr = (w >> 1) * 64, wc = (w & 1) * 64;

    f32x4 acc[4][4];
#pragma unroll
    for (int i = 0; i < 4; i++)
#pragma unroll
        for (int j = 0; j < 4; j++) acc[i][j] = (f32x4){0.f, 0.f, 0.f, 0.f};

    auto stage = [&](int buf, int k0) {
#pragma unroll
        for (int cc = 0; cc < 2; cc++) {
            int c = tid + cc * 256;            // 512 chunks of 8 bf16 per matrix
            int row = c >> 2;
            int chunk = (c & 3) ^ ((row >> 1) & 3);  // pre-swizzled source
            gload_lds16(A + (size_t)(m0 + row) * lda + k0 + chunk * 8, &As[buf][c * 8]);
            gload_lds16(Bw + (size_t)(n0 + row) * ldb + k0 + chunk * 8, &Bs[buf][c * 8]);
        }
    };

    stage(0, 0);
    __syncthreads();                // drains vmcnt(0): buf0 ready
    int cur = 0;
    for (int k0 = 0; k0 < K; k0 += 32) {
        if (k0 + 32 < K) stage(cur ^ 1, k0 + 32);   // async prefetch next tile
        const bf16* Asc = As[cur];
        const bf16* Bsc = Bs[cur];
        bf16x8 af[4], bfr[4];
#pragma unroll
        for (int mi = 0; mi < 4; mi++) {
            int row = wr + mi * 16 + l15;
            int chunkE = quad ^ ((row >> 1) & 3);
            af[mi] = *(const bf16x8*)(&Asc[row * 32 + chunkE * 8]);
        }
#pragma unroll
        for (int ni = 0; ni < 4; ni++) {
            int row = wc + ni * 16 + l15;
            int chunkE = quad ^ ((row >> 1) & 3);
            bfr[ni] = *(const bf16x8*)(&Bsc[row * 32 + chunkE * 8]);
        }
#pragma unroll
        for (int mi = 0; mi < 4; mi++)
#pragma unroll
            for (int ni = 0; ni < 4; ni++)
                acc[mi][ni] = mfma16(af[mi], bfr[ni], acc[mi][ni]);
        __syncthreads();            // prefetch DMA + LDS reads drained; all waves
        cur ^= 1;
    }

#pragma unroll
    for (int mi = 0; mi < 4; mi++) {
#pragma unroll
        for (int ni = 0; ni < 4; ni++) {
            int col = n0 + wc + ni * 16 + l15;
            if (col < N) {
#pragma unroll
                for (int r = 0; r < 4; r++) {
                    int row = m0 + wr + mi * 16 + quad * 4 + r;
                    if (C_F32) ((float*)Cv)[(size_t)row * ldc + col] = acc[mi][ni][r];
                    else       ((bf16*)Cv)[(size_t)row * ldc + col] = (bf16)acc[mi][ni][r];
                }
            }
        }
    }
}

// ---------------------------------------------------------------------------
// In-place row RMSNorm on bf16 buffer, fp32 weight, fp32 stats.
// ---------------------------------------------------------------------------
__global__ void rmsnorm_ip(bf16* __restrict__ buf, const float* __restrict__ w,
                           int cols, int ld) {
    int row = blockIdx.x;
    bf16* p = buf + (size_t)row * ld;
    float ss = 0.f;
    for (int c = threadIdx.x; c < cols; c += 256) {
        float v = __bfloat162float(p[c]);
        ss += v * v;
    }
#pragma unroll
    for (int off = 32; off; off >>= 1) ss += __shfl_down(ss, off, 64);
    __shared__ float red[4];
    __shared__ float rnorm_s;
    if ((threadIdx.x & 63) == 0) red[threadIdx.x >> 6] = ss;
    __syncthreads();
    if (threadIdx.x == 0)
        rnorm_s = rsqrtf((red[0] + red[1] + red[2] + red[3]) / cols + 1e-6f);
    __syncthreads();
    float rn = rnorm_s;
    for (int c = threadIdx.x; c < cols; c += 256) {
        float v = __bfloat162float(p[c]);
        p[c] = (bf16)(v * rn * w[c]);
    }
}

// ---------------------------------------------------------------------------
// RoPE on k_pe: kpe[row,0..64) = rope(cq[row,1024..1088)). fp32 freqs.
// cq row stride 2624 (fused buffer).
// ---------------------------------------------------------------------------
__global__ void rope_k(const bf16* __restrict__ cq, bf16* __restrict__ kpe,
                       const float* __restrict__ fc, const float* __restrict__ fs) {
    int id = blockIdx.x * 256 + threadIdx.x;  // ROWS*32
    int row = id >> 5, i = id & 31;
    int s = row & (S_ - 1);
    const bf16* p = cq + (size_t)row * 2624 + 1024 + 2 * i;
    float x0 = __bfloat162float(p[0]), x1 = __bfloat162float(p[1]);
    float c = fc[s * 32 + i], sn = fs[s * 32 + i];
    bf16* q = kpe + (size_t)row * 64 + 2 * i;
    q[0] = (bf16)(x0 * c - x1 * sn);
    q[1] = (bf16)(x0 * sn + x1 * c);
}

// RoPE on q_pe, in-place on bf16 qbuf: [row, h*128+64 .. h*128+128)
__global__ void rope_q(bf16* __restrict__ qb, const float* __restrict__ fc,
                       const float* __restrict__ fs) {
    int id = blockIdx.x * 256 + threadIdx.x;  // ROWS*16*32
    int row = id >> 9, rest = id & 511, h = rest >> 5, i = rest & 31;
    int s = row & (S_ - 1);
    bf16* p = qb + (size_t)row * 2048 + h * 128 + 64 + 2 * i;
    float x0 = __bfloat162float(p[0]), x1 = __bfloat162float(p[1]);
    float c = fc[s * 32 + i], sn = fs[s * 32 + i];
    p[0] = (bf16)(x0 * c - x1 * sn);
    p[1] = (bf16)(x0 * sn + x1 * c);
}

// ---------------------------------------------------------------------------
// MFMA flash attention, causal, SWAPPED QK^T, SPLIT-T. 512 thr = 8 waves,
// 2 groups x 4 waves; group 0 q-tile jA=blockIdx.x, group 1 q-tile jB=31-jA.
// blockIdx.z = b*2 + half: half 0 stages/computes tiles [0,h0), half 1
// [h0,nt) where nt=jB+1, h0=ceil(nt/2). Each half writes normalized partial
// O (bf16) + per-qrow (m,l) fp32 sidecar; attn_combine merges.
// R13 staging + T13 defer-rescale + in-reg P (R18 k-slot permutation).
// ---------------------------------------------------------------------------
__global__ __launch_bounds__(512) void attn_kernel(const bf16* __restrict__ Qg,
                                                   const bf16* __restrict__ KV2,
                                                   const bf16* __restrict__ KPE,
                                                   bf16* __restrict__ pO0,
                                                   bf16* __restrict__ pO1,
                                                   float2* __restrict__ ml) {
    __shared__ bf16 Ks[64 * 128];       // [t][d], 16B-chunk swizzle cE = c8 ^ (t&7)
    __shared__ bf16 Vt[128 * 64];       // [dv][t], swizzle cE = (t>>3) ^ (dv&7)
    const int tid = threadIdx.x;
    const int h = blockIdx.y;
    const int zz = blockIdx.z;                    // b*2 + half
    const int b = zz >> 1, half = zz & 1;
    const int w = tid >> 6, lane = tid & 63, quad = lane >> 4, l15 = lane & 15;
    const int grp = w >> 2, wl = w & 3;
    const int jB = 31 - (int)blockIdx.x;
    const int q0 = (grp ? jB : (int)blockIdx.x) * 64;
    const int qrow = q0 + wl * 16 + l15;          // this lane's q row (in S)
    const float scl2 = 0.08838834764831845f * LOG2E;  // 1/sqrt(128) * log2(e)

    const int nt = jB + 1;                        // total staged tiles
    const int h0 = (nt + 1) >> 1;                 // tiles in half 0
    const int tlo = half ? h0 * 64 : 0;           // block-uniform bounds
    const int thi = half ? (nt - 1) * 64 : (h0 - 1) * 64;

    // Q as B-fragment: lane holds col q=l15(own row), k = kk*32 + quad*8 + j
    bf16x8 qf[4];
    {
        const bf16* qp = Qg + ((size_t)(b * S_) + qrow) * 2048 + h * 128 + quad * 8;
#pragma unroll
        for (int kk = 0; kk < 4; kk++) qf[kk] = *(const bf16x8*)(qp + kk * 32);
    }

    f32x4 acc_o[8];
#pragma unroll
    for (int j = 0; j < 8; j++) acc_o[j] = (f32x4){0.f, 0.f, 0.f, 0.f};
    float m_i = NEG_BIG, l_i = 0.f;               // per-lane (q = qrow)
    const int s_base = q0 + wl * 16 + quad * 4;   // acc_o row base (PV C-layout)

    // V staging decomposition: thread -> 4t x 4dv transpose-in-regs
    const int dv0 = (tid >> 4) * 4;               // 0..124
    const int tv0 = (tid & 15) * 4;               // 0..60

    for (int t0 = tlo; t0 <= thi; t0 += 64) {
        __syncthreads();
        // ---- stage K: register int4 + swizzled ds_write (R13-proven) ----
#pragma unroll
        for (int cc = 0; cc < 2; cc++) {
            int c = tid + cc * 512;               // 1024 chunks of 8
            int trow = c >> 4, chunk = c & 15;
            int col8 = chunk * 8;
            size_t grow = (size_t)(b * S_) + t0 + trow;
            int4 v;
            if (col8 < 64) v = *(const int4*)(KV2 + grow * 3072 + h * 192 + col8);
            else           v = *(const int4*)(KPE + grow * 64 + col8 - 64);
            int chunkE = chunk ^ (trow & 7);
            *(int4*)(&Ks[trow * 128 + chunkE * 8]) = v;
        }
        // ---- stage V: 4x4 register transpose, 4 ds_write_b64/thread ----
        {
            size_t grow0 = (size_t)(b * S_) + t0 + tv0;
            alignas(16) bf16 va[4][4];
#pragma unroll
            for (int i = 0; i < 4; i++)
                *(uint2*)va[i] = *(const uint2*)(KV2 + (grow0 + i) * 3072 + h * 192 + 64 + dv0);
#pragma unroll
            for (int j = 0; j < 4; j++) {
                alignas(8) bf16 tmp[4] = {va[0][j], va[1][j], va[2][j], va[3][j]};
                int dv = dv0 + j;
                int cE = (tv0 >> 3) ^ (dv & 7);
                *(uint2*)(&Vt[dv * 64 + cE * 8 + (tv0 & 7)]) = *(uint2*)tmp;
            }
        }
        __syncthreads();
        if (t0 > q0) continue;   // this group's causal range done; keep staging

        // ---- scores, swapped: sc[ni] = K_tile(ni) x Q  => D[t][q] ----
        f32x4 sc[4];
#pragma unroll
        for (int ni = 0; ni < 4; ni++) sc[ni] = (f32x4){0.f, 0.f, 0.f, 0.f};
#pragma unroll
        for (int kk = 0; kk < 4; kk++) {
#pragma unroll
            for (int ni = 0; ni < 4; ni++) {
                int trow = ni * 16 + l15;
                int chunkE = (kk * 4 + quad) ^ (trow & 7);
                bf16x8 kf = *(const bf16x8*)(&Ks[trow * 128 + chunkE * 8]);
                sc[ni] = mfma16(kf, qf[kk], sc[ni]);   // A=K rows t, B=Q cols q
            }
        }
        // ---- per-lane softmax over the full row (t in lane) ----
        float xv[4][4];
        float pmax = NEG_BIG;
#pragma unroll
        for (int ni = 0; ni < 4; ni++) {
#pragma unroll
            for (int r = 0; r < 4; r++) {
                int t = t0 + ni * 16 + quad * 4 + r;
                float x = sc[ni][r] * scl2;
                if (t > qrow) x = NEG_BIG;
                xv[ni][r] = x;
                pmax = fmaxf(pmax, x);
            }
        }
        pmax = fmaxf(pmax, __shfl_xor(pmax, 16, 64));
        pmax = fmaxf(pmax, __shfl_xor(pmax, 32, 64));
        // T13 defer-rescale: only rescale when max grew by > 8 (P <= 2^8).
        if (!__all(pmax - m_i <= 8.0f)) {
            float mn = fmaxf(m_i, pmax);
            float alpha = exp2f(m_i - mn);
            m_i = mn;
            l_i *= alpha;
            float ar[4];
#pragma unroll
            for (int r = 0; r < 4; r++) ar[r] = __shfl(alpha, quad * 4 + r, 64);
#pragma unroll
            for (int nj = 0; nj < 8; nj++)
#pragma unroll
                for (int r = 0; r < 4; r++) acc_o[nj][r] *= ar[r];
        }
        float rsum = 0.f;
#pragma unroll
        for (int ni = 0; ni < 4; ni++)
#pragma unroll
            for (int r = 0; r < 4; r++) {
                float e = exp2f(xv[ni][r] - m_i);
                xv[ni][r] = e;
                rsum += e;
            }
        rsum += __shfl_xor(rsum, 16, 64);
        rsum += __shfl_xor(rsum, 32, 64);
        l_i += rsum;

        // ---- O += P @ V, P fully in-register (k-slot permutation pi) ----
#pragma unroll
        for (int sg = 0; sg < 2; sg++) {
            alignas(16) bf16 pfa[8];
#pragma unroll
            for (int j = 0; j < 4; j++) {
                pfa[j]     = (bf16)xv[2 * sg][j];
                pfa[j + 4] = (bf16)xv[2 * sg + 1][j];
            }
            bf16x8 pf = *(const bf16x8*)pfa;
            const int cLo = sg * 4 + (quad >> 1);
            const int cHi = cLo + 2;
            const int off = (quad & 1) * 4;
#pragma unroll
            for (int nj = 0; nj < 8; nj++) {
                int dv = nj * 16 + l15;
                int d7 = dv & 7;
                alignas(16) bf16 vfa[8];
                *(uint2*)&vfa[0] = *(const uint2*)&Vt[dv * 64 + ((cLo ^ d7) * 8) + off];
                *(uint2*)&vfa[4] = *(const uint2*)&Vt[dv * 64 + ((cHi ^ d7) * 8) + off];
                bf16x8 vf = *(const bf16x8*)vfa;
                acc_o[nj] = mfma16(pf, vf, acc_o[nj]);
            }
        }
    }
    // ---- epilogue: write normalized partial O + (m,l) sidecar ----
    float lr[4];
#pragma unroll
    for (int r = 0; r < 4; r++) lr[r] = __shfl(l_i, quad * 4 + r, 64);
    bf16* pO = half ? pO1 : pO0;
#pragma unroll
    for (int nj = 0; nj < 8; nj++) {
        int col = h * 128 + nj * 16 + l15;
#pragma unroll
        for (int r = 0; r < 4; r++) {
            float inv = lr[r] > 0.f ? 1.0f / lr[r] : 0.f;
            float v = acc_o[nj][r] * inv;
            pO[((size_t)(b * S_) + s_base + r) * 2048 + col] = (bf16)v;
        }
    }
    // m_i/l_i uniform across quads (post shfl_xor 16|32 reductions):
    // lanes with quad==0 cover qrow = q0 + wl*16 + 0..15.
    if (quad == 0) ml[((size_t)zz * S_ + qrow) * 16 + h] = make_float2(m_i, l_i);
}

// ---------------------------------------------------------------------------
// Combine split-t partials: O = (p0*w0 + p1*w1)/(w0+w1),
// w_i = l_i * 2^(m_i - max(m0,m1)). 8 elems/thread. In-place into pO0.
// ---------------------------------------------------------------------------
__global__ __launch_bounds__(256) void attn_combine(const bf16* __restrict__ pO0c,
                                                    const bf16* __restrict__ pO1,
                                                    const float2* __restrict__ ml,
                                                    bf16* __restrict__ outb) {
    int i = blockIdx.x * 256 + threadIdx.x;       // 2,097,152 units of 8 elems
    int row = i >> 8;                             // b*2048 + s  (0..8191)
    int u = i & 255;
    int col = u * 8;
    int h = col >> 7;
    int b = row >> 11, s = row & 2047;
    float2 v0 = ml[((size_t)(b * 2 + 0) * S_ + s) * 16 + h];
    float2 v1 = ml[((size_t)(b * 2 + 1) * S_ + s) * 16 + h];
    float M = fmaxf(v0.x, v1.x);
    float w0 = v0.y * exp2f(v0.x - M);
    float w1 = v1.y * exp2f(v1.x - M);
    float inv = 1.0f / (w0 + w1);                 // half0 always has l>0
    size_t base = (size_t)row * 2048 + col;
    uint4 a = *(const uint4*)(pO0c + base);
    uint4 c = *(const uint4*)(pO1 + base);
    const bf16* pa = (const bf16*)&a;
    const bf16* pc = (const bf16*)&c;
    alignas(16) bf16 o[8];
#pragma unroll
    for (int j = 0; j < 8; j++)
        o[j] = (bf16)((__bfloat162float(pa[j]) * w0 + __bfloat162float(pc[j]) * w1) * inv);
    *(uint4*)(outb + base) = *(const uint4*)o;
}

// ---------------------------------------------------------------------------
extern "C" void kernel_launch(void* const* d_in, const int* in_sizes, int n_in,
                              void* d_out, int out_size, void* d_ws, size_t ws_size,
                              hipStream_t stream) {
    const float* x        = (const float*)d_in[0];   // (4096, 2048) fp32
    const float* wq_a     = (const float*)d_in[1];   // (1536, 2048) fp32
    const float* q_norm_w = (const float*)d_in[2];   // (1536,) fp32
    const float* wq_b     = (const float*)d_in[3];   // (2048, 1536) fp32
    const float* wkv_a    = (const float*)d_in[4];   // (1088, 2048) fp32
    const float* kv_norm_w= (const float*)d_in[5];   // (1024,) fp32
    const float* wkv_b    = (const float*)d_in[6];   // (3072, 1024) fp32
    const float* wo       = (const float*)d_in[7];   // (2048, 2048) fp32
    const float* fcos     = (const float*)d_in[9];   // (2048, 32) fp32
    const float* fsin     = (const float*)d_in[10];  // (2048, 32) fp32
    float* out = (float*)d_out;                      // (4096, 2048) fp32

    char* ws = (char*)d_ws;
    bf16* kv2   = (bf16*)(ws);                  // 25.2MB
    bf16* kpe   = (bf16*)(ws + 25165824);       // 0.5MB
    bf16* cq    = (bf16*)(ws + 25690112);       // 21.5MB combined kvb|qa
    bf16* xb    = (bf16*)(ws + 47185920);       // 16.8MB; later pO1
    bf16* wslot = (bf16*)(ws + 63963136);       // 11.0MB weight slot
    bf16* pO0   = cq;                           // partial O half0 (16.8MB)
    float2* ml  = (float2*)(ws + 42467328);     // 2MB sidecar (in cq tail)
    bf16* pO1   = xb;                           // partial O half1
    bf16* attno = cq;                           // combine output (in-place pO0)
    bf16* qbuf  = (bf16*)d_out;                 // bf16 in d_out

    dim3 blk(256);
    // ---- convert x once ----
    f2b<<<8192, blk, 0, stream>>>(x, xb, 2097152);
    // ---- fused A-projections: cq = xb @ [wkv_a; wq_a]^T (N=2624) ----
    f2b<<<2176, blk, 0, stream>>>(wkv_a, wslot, 557056);              // rows 0-1087
    f2b<<<3072, blk, 0, stream>>>(wq_a, wslot + 1088 * 2048, 786432); // rows 1088-2623
    // ragged N=2624: staging reads wslot rows up to 2687 (junk ok, cols>=2624
    // never stored); 2688*2048*2 = 11.01MB fits wslot region.
    gemm_bt<false><<<dim3(32, 21), blk, 0, stream>>>(xb, wslot, cq, 4096, 2624, 2048, 2048, 2048, 2624);
    // ---- KV path ----
    rope_k<<<512, blk, 0, stream>>>(cq, kpe, fcos, fsin);
    rmsnorm_ip<<<4096, blk, 0, stream>>>(cq, kv_norm_w, 1024, 2624);
    f2b<<<3072, blk, 0, stream>>>(wkv_b, wslot, 786432);   // 3072*1024/4
    gemm_bt<false><<<dim3(32, 24), blk, 0, stream>>>(cq, wslot, kv2, 4096, 3072, 1024, 2624, 1024, 3072);
    // ---- Q path (qa = cq cols 1088..2623; qbuf in d_out) ----
    rmsnorm_ip<<<4096, blk, 0, stream>>>(cq + 1088, q_norm_w, 1536, 2624);
    f2b<<<3072, blk, 0, stream>>>(wq_b, wslot, 786432);    // 2048*1536/4
    gemm_bt<false><<<dim3(32, 16), blk, 0, stream>>>(cq + 1088, wslot, qbuf, 4096, 2048, 1536, 2624, 1536, 2048);
    rope_q<<<8192, blk, 0, stream>>>(qbuf, fcos, fsin);
    // ---- attention: split-t (1024 blocks = 4/CU) + combine ----
    attn_kernel<<<dim3(16, 16, 4), dim3(512), 0, stream>>>(qbuf, kv2, kpe, pO0, pO1, ml);
    attn_combine<<<8192, blk, 0, stream>>>(pO0, pO1, ml, attno);
    // ---- output projection (fp32 store) ----
    f2b<<<4096, blk, 0, stream>>>(wo, wslot, 1048576);     // 2048*2048/4
    gemm_bt<true><<<dim3(32, 16), blk, 0, stream>>>(attno, wslot, out, 4096, 2048, 2048, 2048, 2048, 2048);
}

// Round 11
// 480.512 us; speedup vs baseline: 1.1121x; 1.1121x over previous
//
#include <hip/hip_runtime.h>
#include <hip/hip_bf16.h>

// MLA prefill: B=2,S=2048,D=2048,H=16,DQK=128(=64 nope+64 rope),DV=128,QLR=1536,KVLR=1024
// INPUTS FP32; OUTPUT FP32. R20 (post R19 split-t regression):
//  - split-t + combine REVERTED (half-1 blocks had 4/8 waves with zero
//    compute: causal range of small-jA group lives wholly in half 0).
//  - attn: K staging via global_load_lds, made legal by SPLITTING K into
//    uniform-base components: Ks_nope (from KV2) and Ks_pe (from KPE) as
//    separate LDS arrays -- each call full-exec, single affine base (the
//    banned construct was the per-lane ternary BASE SELECT). Swizzle on the
//    per-lane global source (3-bit XOR stays within each region).
//    + K/V LDS DOUBLE-BUFFER with statically-named A/B arrays (unroll x2,
//    alias-free): stage(next) issued before compute(cur), ONE barrier per
//    tile drains the in-flight DMA (flew under compute). LDS 64KB = 2
//    blocks/CU = grid residency (512 blocks) -> zero occupancy cost.
//    V keeps register 4x4 transpose (transient regs only).
//  Kept: swapped QK^T, in-reg P (R18), T13 defer-rescale, fused A-proj,
//        gemm 2-phase dbuf (no T1 swizzle).
//  BANNED: divergent-base global_load_lds. ABANDONED: T14 reg-carriers,
//          split-t partials, T1 on L3-resident GEMMs.
// No __expf (container-killer). No INFINITY (finite-math safe).
//
// Workspace map (74.98MB used; 80MB proven writable in R1):
//   kv2  @ 0         (4096x3072 bf16, 25.2MB)  live: kv2-gemm .. attn
//   kpe  @ 25165824  (4096x64  bf16,  0.5MB)   live: rope_k .. attn
//   cq   @ 25690112  (4096x2624 bf16, 21.5MB)  cols 0-1087=kvb, 1088-2623=qa
//                    reused as attno (4096x2048) after q_b gemm.
//   xb   @ 47185920  (4096x2048 bf16, 16.8MB)  live: cvt .. fused gemm
//   wslot@ 63963136  (11.0MB weight slot: wkv_a+wq_a fused / wkv_b / wq_b / wo)
//   qbuf (4096x2048 bf16) lives in d_out until out-gemm.

using bf16 = __hip_bfloat16;
typedef __attribute__((ext_vector_type(8))) short bf16x8;
typedef __attribute__((ext_vector_type(4))) float f32x4;

#define S_ 2048
#define NEG_BIG (-1e30f)
#define LOG2E 1.4426950408889634f

static __device__ __forceinline__ f32x4 mfma16(bf16x8 a, bf16x8 b, f32x4 c) {
    return __builtin_amdgcn_mfma_f32_16x16x32_bf16(a, b, c, 0, 0, 0);
}

// async global->LDS, 16B per lane. LDS dest must be lane-linear per wave;
// global src per-lane OK, but base must be a single pointer (full exec).
static __device__ __forceinline__ void gload_lds16(const bf16* g, bf16* l) {
    __builtin_amdgcn_global_load_lds(
        (const __attribute__((address_space(1))) void*)g,
        (__attribute__((address_space(3))) void*)l, 16, 0, 0);
}

// ---------------------------------------------------------------------------
// fp32 -> bf16 bulk convert, 4 elems/thread.
// ---------------------------------------------------------------------------
__global__ __launch_bounds__(256) void f2b(const float* __restrict__ src,
                                           bf16* __restrict__ dst, int n4) {
    int i = blockIdx.x * 256 + threadIdx.x;
    if (i < n4) {
        float4 v = ((const float4*)src)[i];
        alignas(8) bf16 t[4];
        t[0] = (bf16)v.x; t[1] = (bf16)v.y; t[2] = (bf16)v.z; t[3] = (bf16)v.w;
        ((uint2*)dst)[i] = *(const uint2*)t;
    }
}

// ---------------------------------------------------------------------------
// GEMM: C[M,N] = A[M,K] @ B[N,K]^T. 128x128 tile, BK=32, 256 thr, bf16 in.
// Double-buffered staging via global_load_lds; swizzle on GLOBAL src address,
// LDS linear. One __syncthreads per K-step (implicit vmcnt+lgkm drain).
// NOTE: no N-guard in staging -- caller guarantees B rows up to grid.y*128
// readable (ragged N reads junk rows; cols>=N never stored).
// ---------------------------------------------------------------------------
template <bool C_F32>
__global__ __launch_bounds__(256) void gemm_bt(const bf16* __restrict__ A,
                                               const bf16* __restrict__ Bw,
                                               void* __restrict__ Cv,
                                               int M, int N, int K,
                                               int lda, int ldb, int ldc) {
    __shared__ bf16 As[2][128 * 32];
    __shared__ bf16 Bs[2][128 * 32];
    const int tid = threadIdx.x;
    const int m0 = blockIdx.x * 128;
    const int n0 = blockIdx.y * 128;
    const int w = tid >> 6, lane = tid & 63, quad = lane >> 4, l15 = lane & 15;
    const int wr = (w >> 1) * 64, wc = (w & 1) * 64;

    f32x4 acc[4][4];
#pragma unroll
    for (int i = 0; i < 4; i++)
#pragma unroll
        for (int j = 0; j < 4; j++) acc[i][j] = (f32x4){0.f, 0.f, 0.f, 0.f};

    auto stage = [&](int buf, int k0) {
#pragma unroll
        for (int cc = 0; cc < 2; cc++) {
            int c = tid + cc * 256;            // 512 chunks of 8 bf16 per matrix
            int row = c >> 2;
            int chunk = (c & 3) ^ ((row >> 1) & 3);  // pre-swizzled source
            gload_lds16(A + (size_t)(m0 + row) * lda + k0 + chunk * 8, &As[buf][c * 8]);
            gload_lds16(Bw + (size_t)(n0 + row) * ldb + k0 + chunk * 8, &Bs[buf][c * 8]);
        }
    };

    stage(0, 0);
    __syncthreads();                // drains vmcnt(0): buf0 ready
    int cur = 0;
    for (int k0 = 0; k0 < K; k0 += 32) {
        if (k0 + 32 < K) stage(cur ^ 1, k0 + 32);   // async prefetch next tile
        const bf16* Asc = As[cur];
        const bf16* Bsc = Bs[cur];
        bf16x8 af[4], bfr[4];
#pragma unroll
        for (int mi = 0; mi < 4; mi++) {
            int row = wr + mi * 16 + l15;
            int chunkE = quad ^ ((row >> 1) & 3);
            af[mi] = *(const bf16x8*)(&Asc[row * 32 + chunkE * 8]);
        }
#pragma unroll
        for (int ni = 0; ni < 4; ni++) {
            int row = wc + ni * 16 + l15;
            int chunkE = quad ^ ((row >> 1) & 3);
            bfr[ni] = *(const bf16x8*)(&Bsc[row * 32 + chunkE * 8]);
        }
#pragma unroll
        for (int mi = 0; mi < 4; mi++)
#pragma unroll
            for (int ni = 0; ni < 4; ni++)
                acc[mi][ni] = mfma16(af[mi], bfr[ni], acc[mi][ni]);
        __syncthreads();            // prefetch DMA + LDS reads drained; all waves
        cur ^= 1;
    }

#pragma unroll
    for (int mi = 0; mi < 4; mi++) {
#pragma unroll
        for (int ni = 0; ni < 4; ni++) {
            int col = n0 + wc + ni * 16 + l15;
            if (col < N) {
#pragma unroll
                for (int r = 0; r < 4; r++) {
                    int row = m0 + wr + mi * 16 + quad * 4 + r;
                    if (C_F32) ((float*)Cv)[(size_t)row * ldc + col] = acc[mi][ni][r];
                    else       ((bf16*)Cv)[(size_t)row * ldc + col] = (bf16)acc[mi][ni][r];
                }
            }
        }
    }
}

// ---------------------------------------------------------------------------
// In-place row RMSNorm on bf16 buffer, fp32 weight, fp32 stats.
// ---------------------------------------------------------------------------
__global__ void rmsnorm_ip(bf16* __restrict__ buf, const float* __restrict__ w,
                           int cols, int ld) {
    int row = blockIdx.x;
    bf16* p = buf + (size_t)row * ld;
    float ss = 0.f;
    for (int c = threadIdx.x; c < cols; c += 256) {
        float v = __bfloat162float(p[c]);
        ss += v * v;
    }
#pragma unroll
    for (int off = 32; off; off >>= 1) ss += __shfl_down(ss, off, 64);
    __shared__ float red[4];
    __shared__ float rnorm_s;
    if ((threadIdx.x & 63) == 0) red[threadIdx.x >> 6] = ss;
    __syncthreads();
    if (threadIdx.x == 0)
        rnorm_s = rsqrtf((red[0] + red[1] + red[2] + red[3]) / cols + 1e-6f);
    __syncthreads();
    float rn = rnorm_s;
    for (int c = threadIdx.x; c < cols; c += 256) {
        float v = __bfloat162float(p[c]);
        p[c] = (bf16)(v * rn * w[c]);
    }
}

// ---------------------------------------------------------------------------
// RoPE on k_pe: kpe[row,0..64) = rope(cq[row,1024..1088)). fp32 freqs.
// cq row stride 2624 (fused buffer).
// ---------------------------------------------------------------------------
__global__ void rope_k(const bf16* __restrict__ cq, bf16* __restrict__ kpe,
                       const float* __restrict__ fc, const float* __restrict__ fs) {
    int id = blockIdx.x * 256 + threadIdx.x;  // ROWS*32
    int row = id >> 5, i = id & 31;
    int s = row & (S_ - 1);
    const bf16* p = cq + (size_t)row * 2624 + 1024 + 2 * i;
    float x0 = __bfloat162float(p[0]), x1 = __bfloat162float(p[1]);
    float c = fc[s * 32 + i], sn = fs[s * 32 + i];
    bf16* q = kpe + (size_t)row * 64 + 2 * i;
    q[0] = (bf16)(x0 * c - x1 * sn);
    q[1] = (bf16)(x0 * sn + x1 * c);
}

// RoPE on q_pe, in-place on bf16 qbuf: [row, h*128+64 .. h*128+128)
__global__ void rope_q(bf16* __restrict__ qb, const float* __restrict__ fc,
                       const float* __restrict__ fs) {
    int id = blockIdx.x * 256 + threadIdx.x;  // ROWS*16*32
    int row = id >> 9, rest = id & 511, h = rest >> 5, i = rest & 31;
    int s = row & (S_ - 1);
    bf16* p = qb + (size_t)row * 2048 + h * 128 + 64 + 2 * i;
    float x0 = __bfloat162float(p[0]), x1 = __bfloat162float(p[1]);
    float c = fc[s * 32 + i], sn = fs[s * 32 + i];
    p[0] = (bf16)(x0 * c - x1 * sn);
    p[1] = (bf16)(x0 * sn + x1 * c);
}

// ---------------------------------------------------------------------------
// MFMA flash attention, causal, SWAPPED QK^T. Block = 512 thr = 8 waves,
// 2 groups x 4 waves; group 0 q-tile blockIdx.x, group 1 q-tile 31-x.
// DOUBLE-BUFFERED K/V (static A/B arrays, unroll x2): K staged by two
// uniform-base global_load_lds calls (nope from KV2, pe from KPE; swizzle on
// global src); V by register 4x4 transpose. One barrier per tile.
// In-reg P PV (R18 k-slot permutation) + T13 defer-rescale.
// ---------------------------------------------------------------------------
__global__ __launch_bounds__(512) void attn_kernel(const bf16* __restrict__ Qg,
                                                   const bf16* __restrict__ KV2,
                                                   const bf16* __restrict__ KPE,
                                                   bf16* __restrict__ Og) {
    // K: split nope/pe, each [64][64], chunk-swizzle within region:
    //   dest chunk c3 of row t holds source col-chunk (c3 ^ (t&7)).
    __shared__ bf16 KnA[64 * 64], KpA[64 * 64];
    __shared__ bf16 KnB[64 * 64], KpB[64 * 64];
    // V transposed [dv][t], swizzle cE = (t>>3) ^ (dv&7).
    __shared__ bf16 VtA[128 * 64], VtB[128 * 64];
    const int tid = threadIdx.x;
    const int h = blockIdx.y;
    const int b = blockIdx.z;
    const int w = tid >> 6, lane = tid & 63, quad = lane >> 4, l15 = lane & 15;
    const int grp = w >> 2, wl = w & 3;
    const int jB = 31 - (int)blockIdx.x;
    const int q0 = (grp ? jB : (int)blockIdx.x) * 64;
    const int qrow = q0 + wl * 16 + l15;          // this lane's q row (in S)
    const float scl2 = 0.08838834764831845f * LOG2E;  // 1/sqrt(128) * log2(e)

    // Q as B-fragment: lane holds col q=l15(own row), k = kk*32 + quad*8 + j
    bf16x8 qf[4];
    {
        const bf16* qp = Qg + ((size_t)(b * S_) + qrow) * 2048 + h * 128 + quad * 8;
#pragma unroll
        for (int kk = 0; kk < 4; kk++) qf[kk] = *(const bf16x8*)(qp + kk * 32);
    }

    f32x4 acc_o[8];
#pragma unroll
    for (int j = 0; j < 8; j++) acc_o[j] = (f32x4){0.f, 0.f, 0.f, 0.f};
    float m_i = NEG_BIG, l_i = 0.f;               // per-lane (q = qrow)
    const int s_base = q0 + wl * 16 + quad * 4;   // acc_o row base (PV C-layout)
    const int tend = jB * 64;                     // block-uniform loop bound

    // staging decompositions
    const int ktrow = tid >> 3, kc3 = tid & 7;    // K: 512 chunks per region
    const int dv0 = (tid >> 4) * 4;               // V: 0..124
    const int tv0 = (tid & 15) * 4;               //    0..60

    auto stageK = [&](bf16* Kn, bf16* Kp, int t0) {
        size_t grow = (size_t)(b * S_) + t0 + ktrow;
        int cs = (kc3 ^ (ktrow & 7)) * 8;
        gload_lds16(KV2 + grow * 3072 + h * 192 + cs, Kn + tid * 8);
        gload_lds16(KPE + grow * 64 + cs, Kp + tid * 8);
    };
    auto stageV = [&](bf16* Vt, int t0) {
        size_t grow0 = (size_t)(b * S_) + t0 + tv0;
        alignas(16) bf16 va[4][4];
#pragma unroll
        for (int i = 0; i < 4; i++)
            *(uint2*)va[i] = *(const uint2*)(KV2 + (grow0 + i) * 3072 + h * 192 + 64 + dv0);
#pragma unroll
        for (int j = 0; j < 4; j++) {
            alignas(8) bf16 tmp[4] = {va[0][j], va[1][j], va[2][j], va[3][j]};
            int dv = dv0 + j;
            int cE = (tv0 >> 3) ^ (dv & 7);
            *(uint2*)(&Vt[dv * 64 + cE * 8 + (tv0 & 7)]) = *(uint2*)tmp;
        }
    };
    auto compute = [&](const bf16* Kn, const bf16* Kp, const bf16* Vt, int t0) {
        // ---- scores, swapped: sc[ni] = K_tile(ni) x Q  => D[t][q] ----
        f32x4 sc[4];
#pragma unroll
        for (int ni = 0; ni < 4; ni++) sc[ni] = (f32x4){0.f, 0.f, 0.f, 0.f};
#pragma unroll
        for (int kk = 0; kk < 4; kk++) {
#pragma unroll
            for (int ni = 0; ni < 4; ni++) {
                int trow = ni * 16 + l15;
                bf16x8 kf;
                if (kk < 2) {
                    int c3 = (kk * 4 + quad) ^ (trow & 7);
                    kf = *(const bf16x8*)(&Kn[trow * 64 + c3 * 8]);
                } else {
                    int c3 = ((kk - 2) * 4 + quad) ^ (trow & 7);
                    kf = *(const bf16x8*)(&Kp[trow * 64 + c3 * 8]);
                }
                sc[ni] = mfma16(kf, qf[kk], sc[ni]);   // A=K rows t, B=Q cols q
            }
        }
        // ---- per-lane softmax over the full row (t in lane) ----
        float xv[4][4];
        float pmax = NEG_BIG;
#pragma unroll
        for (int ni = 0; ni < 4; ni++) {
#pragma unroll
            for (int r = 0; r < 4; r++) {
                int t = t0 + ni * 16 + quad * 4 + r;
                float x = sc[ni][r] * scl2;
                if (t > qrow) x = NEG_BIG;
                xv[ni][r] = x;
                pmax = fmaxf(pmax, x);
            }
        }
        pmax = fmaxf(pmax, __shfl_xor(pmax, 16, 64));
        pmax = fmaxf(pmax, __shfl_xor(pmax, 32, 64));
        // T13 defer-rescale: only rescale when max grew by > 8 (P <= 2^8).
        if (!__all(pmax - m_i <= 8.0f)) {
            float mn = fmaxf(m_i, pmax);
            float alpha = exp2f(m_i - mn);
            m_i = mn;
            l_i *= alpha;
            float ar[4];
#pragma unroll
            for (int r = 0; r < 4; r++) ar[r] = __shfl(alpha, quad * 4 + r, 64);
#pragma unroll
            for (int nj = 0; nj < 8; nj++)
#pragma unroll
                for (int r = 0; r < 4; r++) acc_o[nj][r] *= ar[r];
        }
        float rsum = 0.f;
#pragma unroll
        for (int ni = 0; ni < 4; ni++)
#pragma unroll
            for (int r = 0; r < 4; r++) {
                float e = exp2f(xv[ni][r] - m_i);
                xv[ni][r] = e;
                rsum += e;
            }
        rsum += __shfl_xor(rsum, 16, 64);
        rsum += __shfl_xor(rsum, 32, 64);
        l_i += rsum;

        // ---- O += P @ V, P fully in-register (k-slot permutation pi) ----
#pragma unroll
        for (int sg = 0; sg < 2; sg++) {
            alignas(16) bf16 pfa[8];
#pragma unroll
            for (int j = 0; j < 4; j++) {
                pfa[j]     = (bf16)xv[2 * sg][j];
                pfa[j + 4] = (bf16)xv[2 * sg + 1][j];
            }
            bf16x8 pf = *(const bf16x8*)pfa;
            const int cLo = sg * 4 + (quad >> 1);
            const int cHi = cLo + 2;
            const int off = (quad & 1) * 4;
#pragma unroll
            for (int nj = 0; nj < 8; nj++) {
                int dv = nj * 16 + l15;
                int d7 = dv & 7;
                alignas(16) bf16 vfa[8];
                *(uint2*)&vfa[0] = *(const uint2*)&Vt[dv * 64 + ((cLo ^ d7) * 8) + off];
                *(uint2*)&vfa[4] = *(const uint2*)&Vt[dv * 64 + ((cHi ^ d7) * 8) + off];
                bf16x8 vf = *(const bf16x8*)vfa;
                acc_o[nj] = mfma16(pf, vf, acc_o[nj]);
            }
        }
    };

    // ---- prologue: stage tile 0 into A ----
    stageK(KnA, KpA, 0);
    stageV(VtA, 0);
    __syncthreads();              // drains K-DMA (vmcnt) + V writes (lgkm)

    // ---- main loop, unrolled x2 over static buffers ----
    for (int t0 = 0; t0 <= tend; t0 += 128) {
        // phase A: compute tile t0 from A; prefetch t0+64 into B
        if (t0 + 64 <= tend) { stageK(KnB, KpB, t0 + 64); stageV(VtB, t0 + 64); }
        if (t0 <= q0) compute(KnA, KpA, VtA, t0);
        __syncthreads();
        // phase B: compute tile t0+64 from B; prefetch t0+128 into A
        if (t0 + 64 <= tend) {
            if (t0 + 128 <= tend) { stageK(KnA, KpA, t0 + 128); stageV(VtA, t0 + 128); }
            if (t0 + 64 <= q0) compute(KnB, KpB, VtB, t0 + 64);
            __syncthreads();
        }
    }
    // epilogue: l for acc rows fetched from lane l15 = quad*4+r
    float lr[4];
#pragma unroll
    for (int r = 0; r < 4; r++) lr[r] = __shfl(l_i, quad * 4 + r, 64);
#pragma unroll
    for (int nj = 0; nj < 8; nj++) {
        int col = h * 128 + nj * 16 + l15;
#pragma unroll
        for (int r = 0; r < 4; r++) {
            float v = acc_o[nj][r] / lr[r];
            Og[((size_t)(b * S_) + s_base + r) * 2048 + col] = (bf16)v;
        }
    }
}

// ---------------------------------------------------------------------------
extern "C" void kernel_launch(void* const* d_in, const int* in_sizes, int n_in,
                              void* d_out, int out_size, void* d_ws, size_t ws_size,
                              hipStream_t stream) {
    const float* x        = (const float*)d_in[0];   // (4096, 2048) fp32
    const float* wq_a     = (const float*)d_in[1];   // (1536, 2048) fp32
    const float* q_norm_w = (const float*)d_in[2];   // (1536,) fp32
    const float* wq_b     = (const float*)d_in[3];   // (2048, 1536) fp32
    const float* wkv_a    = (const float*)d_in[4];   // (1088, 2048) fp32
    const float* kv_norm_w= (const float*)d_in[5];   // (1024,) fp32
    const float* wkv_b    = (const float*)d_in[6];   // (3072, 1024) fp32
    const float* wo       = (const float*)d_in[7];   // (2048, 2048) fp32
    const float* fcos     = (const float*)d_in[9];   // (2048, 32) fp32
    const float* fsin     = (const float*)d_in[10];  // (2048, 32) fp32
    float* out = (float*)d_out;                      // (4096, 2048) fp32

    char* ws = (char*)d_ws;
    bf16* kv2   = (bf16*)(ws);                  // 25.2MB
    bf16* kpe   = (bf16*)(ws + 25165824);       // 0.5MB
    bf16* cq    = (bf16*)(ws + 25690112);       // 21.5MB combined kvb|qa; attno later
    bf16* xb    = (bf16*)(ws + 47185920);       // 16.8MB
    bf16* wslot = (bf16*)(ws + 63963136);       // 11.0MB weight slot
    bf16* attno = cq;                           // reuse after q_b gemm
    bf16* qbuf  = (bf16*)d_out;                 // bf16 in d_out

    dim3 blk(256);
    // ---- convert x once ----
    f2b<<<8192, blk, 0, stream>>>(x, xb, 2097152);
    // ---- fused A-projections: cq = xb @ [wkv_a; wq_a]^T (N=2624) ----
    f2b<<<2176, blk, 0, stream>>>(wkv_a, wslot, 557056);              // rows 0-1087
    f2b<<<3072, blk, 0, stream>>>(wq_a, wslot + 1088 * 2048, 786432); // rows 1088-2623
    // ragged N=2624: staging reads wslot rows up to 2687 (junk ok, cols>=2624
    // never stored); 2688*2048*2 = 11.01MB fits wslot region.
    gemm_bt<false><<<dim3(32, 21), blk, 0, stream>>>(xb, wslot, cq, 4096, 2624, 2048, 2048, 2048, 2624);
    // ---- KV path ----
    rope_k<<<512, blk, 0, stream>>>(cq, kpe, fcos, fsin);
    rmsnorm_ip<<<4096, blk, 0, stream>>>(cq, kv_norm_w, 1024, 2624);
    f2b<<<3072, blk, 0, stream>>>(wkv_b, wslot, 786432);   // 3072*1024/4
    gemm_bt<false><<<dim3(32, 24), blk, 0, stream>>>(cq, wslot, kv2, 4096, 3072, 1024, 2624, 1024, 3072);
    // ---- Q path (qa = cq cols 1088..2623; qbuf in d_out) ----
    rmsnorm_ip<<<4096, blk, 0, stream>>>(cq + 1088, q_norm_w, 1536, 2624);
    f2b<<<3072, blk, 0, stream>>>(wq_b, wslot, 786432);    // 2048*1536/4
    gemm_bt<false><<<dim3(32, 16), blk, 0, stream>>>(cq + 1088, wslot, qbuf, 4096, 2048, 1536, 2624, 1536, 2048);
    rope_q<<<8192, blk, 0, stream>>>(qbuf, fcos, fsin);
    // ---- attention (cq region becomes attno) ----
    attn_kernel<<<dim3(16, 16, 2), dim3(512), 0, stream>>>(qbuf, kv2, kpe, attno);
    // ---- output projection (fp32 store) ----
    f2b<<<4096, blk, 0, stream>>>(wo, wslot, 1048576);     // 2048*2048/4
    gemm_bt<true><<<dim3(32, 16), blk, 0, stream>>>(attno, wslot, out, 4096, 2048, 2048, 2048, 2048, 2048);
}

// Round 12
// 472.831 us; speedup vs baseline: 1.1301x; 1.0162x over previous
//
#include <hip/hip_runtime.h>
#include <hip/hip_bf16.h>

// MLA prefill: B=2,S=2048,D=2048,H=16,DQK=128(=64 nope+64 rope),DV=128,QLR=1536,KVLR=1024
// INPUTS FP32; OUTPUT FP32. R21 (on R20=480.5us):
//  (a) attn: REVERTED to R18-exact (122.1us proven): 2-barrier stage->compute,
//      K via register int4 + swizzled ds_write, V 4x4 reg transpose, in-reg P
//      PV, T13 defer-rescale, 32KB LDS. (R20 dbuf attn = 128.5, dropped --
//      implicit wave overlap already covers staging at 2 blk/CU x 8 waves.)
//  (b) gemm_bt: 8 WAVES (512 thr) per 128x128 tile -- grids are 512-768
//      blocks = 2-3 blk/CU, so 4-wave blocks gave only 8-12 waves/CU
//      (2-3/SIMD, latency-starved). Same tile/staging/dbuf; each wave owns
//      64x32 (acc[4][2]); per-thread staging halves. Presence doubles.
//  BANNED: divergent-base global_load_lds. ABANDONED: T14 reg-carriers,
//          split-t partials, T1 on L3-resident GEMMs, attn dbuf.
// No __expf (container-killer). No INFINITY (finite-math safe).
//
// Workspace map (74.98MB used; 80MB proven writable in R1):
//   kv2  @ 0         (4096x3072 bf16, 25.2MB)  live: kv2-gemm .. attn
//   kpe  @ 25165824  (4096x64  bf16,  0.5MB)   live: rope_k .. attn
//   cq   @ 25690112  (4096x2624 bf16, 21.5MB)  cols 0-1087=kvb, 1088-2623=qa
//                    reused as attno (4096x2048) after q_b gemm.
//   xb   @ 47185920  (4096x2048 bf16, 16.8MB)  live: cvt .. fused gemm
//   wslot@ 63963136  (11.0MB weight slot: wkv_a+wq_a fused / wkv_b / wq_b / wo)
//   qbuf (4096x2048 bf16) lives in d_out until out-gemm.

using bf16 = __hip_bfloat16;
typedef __attribute__((ext_vector_type(8))) short bf16x8;
typedef __attribute__((ext_vector_type(4))) float f32x4;

#define S_ 2048
#define NEG_BIG (-1e30f)
#define LOG2E 1.4426950408889634f

static __device__ __forceinline__ f32x4 mfma16(bf16x8 a, bf16x8 b, f32x4 c) {
    return __builtin_amdgcn_mfma_f32_16x16x32_bf16(a, b, c, 0, 0, 0);
}

// async global->LDS, 16B per lane. LDS dest must be lane-linear per wave;
// global src must be a single affine base (no divergent base select!).
static __device__ __forceinline__ void gload_lds16(const bf16* g, bf16* l) {
    __builtin_amdgcn_global_load_lds(
        (const __attribute__((address_space(1))) void*)g,
        (__attribute__((address_space(3))) void*)l, 16, 0, 0);
}

// ---------------------------------------------------------------------------
// fp32 -> bf16 bulk convert, 4 elems/thread.
// ---------------------------------------------------------------------------
__global__ __launch_bounds__(256) void f2b(const float* __restrict__ src,
                                           bf16* __restrict__ dst, int n4) {
    int i = blockIdx.x * 256 + threadIdx.x;
    if (i < n4) {
        float4 v = ((const float4*)src)[i];
        alignas(8) bf16 t[4];
        t[0] = (bf16)v.x; t[1] = (bf16)v.y; t[2] = (bf16)v.z; t[3] = (bf16)v.w;
        ((uint2*)dst)[i] = *(const uint2*)t;
    }
}

// ---------------------------------------------------------------------------
// GEMM: C[M,N] = A[M,K] @ B[N,K]^T. 128x128 tile, BK=32, 512 thr = 8 waves
// (each wave owns a 64x32 sub-tile: wr=(w>>2)*64, wc=(w&3)*32, acc[4][2]).
// Double-buffered staging via global_load_lds; swizzle on GLOBAL src address,
// LDS linear. One __syncthreads per K-step (implicit vmcnt+lgkm drain).
// NOTE: no N-guard in staging -- caller guarantees B rows up to grid.y*128
// readable (ragged N reads junk rows; cols>=N never stored).
// ---------------------------------------------------------------------------
template <bool C_F32>
__global__ __launch_bounds__(512) void gemm_bt(const bf16* __restrict__ A,
                                               const bf16* __restrict__ Bw,
                                               void* __restrict__ Cv,
                                               int M, int N, int K,
                                               int lda, int ldb, int ldc) {
    __shared__ bf16 As[2][128 * 32];
    __shared__ bf16 Bs[2][128 * 32];
    const int tid = threadIdx.x;
    const int m0 = blockIdx.x * 128;
    const int n0 = blockIdx.y * 128;
    const int w = tid >> 6, lane = tid & 63, quad = lane >> 4, l15 = lane & 15;
    const int wr = (w >> 2) * 64, wc = (w & 3) * 32;

    f32x4 acc[4][2];
#pragma unroll
    for (int i = 0; i < 4; i++)
#pragma unroll
        for (int j = 0; j < 2; j++) acc[i][j] = (f32x4){0.f, 0.f, 0.f, 0.f};

    auto stage = [&](int buf, int k0) {
        int c = tid;                           // 512 chunks of 8 bf16 per matrix
        int row = c >> 2;
        int chunk = (c & 3) ^ ((row >> 1) & 3);  // pre-swizzled source
        gload_lds16(A + (size_t)(m0 + row) * lda + k0 + chunk * 8, &As[buf][c * 8]);
        gload_lds16(Bw + (size_t)(n0 + row) * ldb + k0 + chunk * 8, &Bs[buf][c * 8]);
    };

    stage(0, 0);
    __syncthreads();                // drains vmcnt(0): buf0 ready
    int cur = 0;
    for (int k0 = 0; k0 < K; k0 += 32) {
        if (k0 + 32 < K) stage(cur ^ 1, k0 + 32);   // async prefetch next tile
        const bf16* Asc = As[cur];
        const bf16* Bsc = Bs[cur];
        bf16x8 af[4], bfr[2];
#pragma unroll
        for (int mi = 0; mi < 4; mi++) {
            int row = wr + mi * 16 + l15;
            int chunkE = quad ^ ((row >> 1) & 3);
            af[mi] = *(const bf16x8*)(&Asc[row * 32 + chunkE * 8]);
        }
#pragma unroll
        for (int ni = 0; ni < 2; ni++) {
            int row = wc + ni * 16 + l15;
            int chunkE = quad ^ ((row >> 1) & 3);
            bfr[ni] = *(const bf16x8*)(&Bsc[row * 32 + chunkE * 8]);
        }
#pragma unroll
        for (int mi = 0; mi < 4; mi++)
#pragma unroll
            for (int ni = 0; ni < 2; ni++)
                acc[mi][ni] = mfma16(af[mi], bfr[ni], acc[mi][ni]);
        __syncthreads();            // prefetch DMA + LDS reads drained; all waves
        cur ^= 1;
    }

#pragma unroll
    for (int mi = 0; mi < 4; mi++) {
#pragma unroll
        for (int ni = 0; ni < 2; ni++) {
            int col = n0 + wc + ni * 16 + l15;
            if (col < N) {
#pragma unroll
                for (int r = 0; r < 4; r++) {
                    int row = m0 + wr + mi * 16 + quad * 4 + r;
                    if (C_F32) ((float*)Cv)[(size_t)row * ldc + col] = acc[mi][ni][r];
                    else       ((bf16*)Cv)[(size_t)row * ldc + col] = (bf16)acc[mi][ni][r];
                }
            }
        }
    }
}

// ---------------------------------------------------------------------------
// In-place row RMSNorm on bf16 buffer, fp32 weight, fp32 stats.
// ---------------------------------------------------------------------------
__global__ void rmsnorm_ip(bf16* __restrict__ buf, const float* __restrict__ w,
                           int cols, int ld) {
    int row = blockIdx.x;
    bf16* p = buf + (size_t)row * ld;
    float ss = 0.f;
    for (int c = threadIdx.x; c < cols; c += 256) {
        float v = __bfloat162float(p[c]);
        ss += v * v;
    }
#pragma unroll
    for (int off = 32; off; off >>= 1) ss += __shfl_down(ss, off, 64);
    __shared__ float red[4];
    __shared__ float rnorm_s;
    if ((threadIdx.x & 63) == 0) red[threadIdx.x >> 6] = ss;
    __syncthreads();
    if (threadIdx.x == 0)
        rnorm_s = rsqrtf((red[0] + red[1] + red[2] + red[3]) / cols + 1e-6f);
    __syncthreads();
    float rn = rnorm_s;
    for (int c = threadIdx.x; c < cols; c += 256) {
        float v = __bfloat162float(p[c]);
        p[c] = (bf16)(v * rn * w[c]);
    }
}

// ---------------------------------------------------------------------------
// RoPE on k_pe: kpe[row,0..64) = rope(cq[row,1024..1088)). fp32 freqs.
// cq row stride 2624 (fused buffer).
// ---------------------------------------------------------------------------
__global__ void rope_k(const bf16* __restrict__ cq, bf16* __restrict__ kpe,
                       const float* __restrict__ fc, const float* __restrict__ fs) {
    int id = blockIdx.x * 256 + threadIdx.x;  // ROWS*32
    int row = id >> 5, i = id & 31;
    int s = row & (S_ - 1);
    const bf16* p = cq + (size_t)row * 2624 + 1024 + 2 * i;
    float x0 = __bfloat162float(p[0]), x1 = __bfloat162float(p[1]);
    float c = fc[s * 32 + i], sn = fs[s * 32 + i];
    bf16* q = kpe + (size_t)row * 64 + 2 * i;
    q[0] = (bf16)(x0 * c - x1 * sn);
    q[1] = (bf16)(x0 * sn + x1 * c);
}

// RoPE on q_pe, in-place on bf16 qbuf: [row, h*128+64 .. h*128+128)
__global__ void rope_q(bf16* __restrict__ qb, const float* __restrict__ fc,
                       const float* __restrict__ fs) {
    int id = blockIdx.x * 256 + threadIdx.x;  // ROWS*16*32
    int row = id >> 9, rest = id & 511, h = rest >> 5, i = rest & 31;
    int s = row & (S_ - 1);
    bf16* p = qb + (size_t)row * 2048 + h * 128 + 64 + 2 * i;
    float x0 = __bfloat162float(p[0]), x1 = __bfloat162float(p[1]);
    float c = fc[s * 32 + i], sn = fs[s * 32 + i];
    p[0] = (bf16)(x0 * c - x1 * sn);
    p[1] = (bf16)(x0 * sn + x1 * c);
}

// ---------------------------------------------------------------------------
// MFMA flash attention, causal, SWAPPED QK^T (R18-exact). 512 thr = 8 waves,
// 2 groups x 4 waves; group 0 q-tile blockIdx.x, group 1 q-tile 31-x.
// R13 staging + T13 defer-rescale + in-register P (PV k-slot permutation).
// LDS = Ks + Vt only (32KB).
// ---------------------------------------------------------------------------
__global__ __launch_bounds__(512) void attn_kernel(const bf16* __restrict__ Qg,
                                                   const bf16* __restrict__ KV2,
                                                   const bf16* __restrict__ KPE,
                                                   bf16* __restrict__ Og) {
    __shared__ bf16 Ks[64 * 128];       // [t][d], 16B-chunk swizzle cE = c8 ^ (t&7)
    __shared__ bf16 Vt[128 * 64];       // [dv][t], swizzle cE = (t>>3) ^ (dv&7)
    const int tid = threadIdx.x;
    const int h = blockIdx.y;
    const int b = blockIdx.z;
    const int w = tid >> 6, lane = tid & 63, quad = lane >> 4, l15 = lane & 15;
    const int grp = w >> 2, wl = w & 3;
    const int jB = 31 - (int)blockIdx.x;
    const int q0 = (grp ? jB : (int)blockIdx.x) * 64;
    const int qrow = q0 + wl * 16 + l15;          // this lane's q row (in S)
    const float scl2 = 0.08838834764831845f * LOG2E;  // 1/sqrt(128) * log2(e)

    // Q as B-fragment: lane holds col q=l15(own row), k = kk*32 + quad*8 + j
    bf16x8 qf[4];
    {
        const bf16* qp = Qg + ((size_t)(b * S_) + qrow) * 2048 + h * 128 + quad * 8;
#pragma unroll
        for (int kk = 0; kk < 4; kk++) qf[kk] = *(const bf16x8*)(qp + kk * 32);
    }

    f32x4 acc_o[8];
#pragma unroll
    for (int j = 0; j < 8; j++) acc_o[j] = (f32x4){0.f, 0.f, 0.f, 0.f};
    float m_i = NEG_BIG, l_i = 0.f;               // per-lane (q = qrow)
    const int s_base = q0 + wl * 16 + quad * 4;   // acc_o row base (PV C-layout)
    const int tend = jB * 64;                     // block-uniform loop bound

    // V staging decomposition: thread -> 4t x 4dv transpose-in-regs
    const int dv0 = (tid >> 4) * 4;               // 0..124
    const int tv0 = (tid & 15) * 4;               // 0..60

    for (int t0 = 0; t0 <= tend; t0 += 64) {
        __syncthreads();
        // ---- stage K: register int4 + swizzled ds_write (R13-proven) ----
#pragma unroll
        for (int cc = 0; cc < 2; cc++) {
            int c = tid + cc * 512;               // 1024 chunks of 8
            int trow = c >> 4, chunk = c & 15;
            int col8 = chunk * 8;
            size_t grow = (size_t)(b * S_) + t0 + trow;
            int4 v;
            if (col8 < 64) v = *(const int4*)(KV2 + grow * 3072 + h * 192 + col8);
            else           v = *(const int4*)(KPE + grow * 64 + col8 - 64);
            int chunkE = chunk ^ (trow & 7);
            *(int4*)(&Ks[trow * 128 + chunkE * 8]) = v;
        }
        // ---- stage V: 4x4 register transpose, 4 ds_write_b64/thread ----
        {
            size_t grow0 = (size_t)(b * S_) + t0 + tv0;
            alignas(16) bf16 va[4][4];
#pragma unroll
            for (int i = 0; i < 4; i++)
                *(uint2*)va[i] = *(const uint2*)(KV2 + (grow0 + i) * 3072 + h * 192 + 64 + dv0);
#pragma unroll
            for (int j = 0; j < 4; j++) {
                alignas(8) bf16 tmp[4] = {va[0][j], va[1][j], va[2][j], va[3][j]};
                int dv = dv0 + j;
                int cE = (tv0 >> 3) ^ (dv & 7);
                *(uint2*)(&Vt[dv * 64 + cE * 8 + (tv0 & 7)]) = *(uint2*)tmp;
            }
        }
        __syncthreads();
        if (t0 > q0) continue;   // this group's causal range done; keep staging

        // ---- scores, swapped: sc[ni] = K_tile(ni) x Q  => D[t][q] ----
        f32x4 sc[4];
#pragma unroll
        for (int ni = 0; ni < 4; ni++) sc[ni] = (f32x4){0.f, 0.f, 0.f, 0.f};
#pragma unroll
        for (int kk = 0; kk < 4; kk++) {
#pragma unroll
            for (int ni = 0; ni < 4; ni++) {
                int trow = ni * 16 + l15;
                int chunkE = (kk * 4 + quad) ^ (trow & 7);
                bf16x8 kf = *(const bf16x8*)(&Ks[trow * 128 + chunkE * 8]);
                sc[ni] = mfma16(kf, qf[kk], sc[ni]);   // A=K rows t, B=Q cols q
            }
        }
        // ---- per-lane softmax over the full row (t in lane) ----
        float xv[4][4];
        float pmax = NEG_BIG;
#pragma unroll
        for (int ni = 0; ni < 4; ni++) {
#pragma unroll
            for (int r = 0; r < 4; r++) {
                int t = t0 + ni * 16 + quad * 4 + r;
                float x = sc[ni][r] * scl2;
                if (t > qrow) x = NEG_BIG;
                xv[ni][r] = x;
                pmax = fmaxf(pmax, x);
            }
        }
        pmax = fmaxf(pmax, __shfl_xor(pmax, 16, 64));
        pmax = fmaxf(pmax, __shfl_xor(pmax, 32, 64));
        // T13 defer-rescale: only rescale when max grew by > 8 (P <= 2^8).
        // First tile: m_i = -1e30 -> always takes the rescale path.
        if (!__all(pmax - m_i <= 8.0f)) {
            float mn = fmaxf(m_i, pmax);
            float alpha = exp2f(m_i - mn);
            m_i = mn;
            l_i *= alpha;
            float ar[4];
#pragma unroll
            for (int r = 0; r < 4; r++) ar[r] = __shfl(alpha, quad * 4 + r, 64);
#pragma unroll
            for (int nj = 0; nj < 8; nj++)
#pragma unroll
                for (int r = 0; r < 4; r++) acc_o[nj][r] *= ar[r];
        }
        float rsum = 0.f;
#pragma unroll
        for (int ni = 0; ni < 4; ni++)
#pragma unroll
            for (int r = 0; r < 4; r++) {
                float e = exp2f(xv[ni][r] - m_i);
                xv[ni][r] = e;
                rsum += e;
            }
        rsum += __shfl_xor(rsum, 16, 64);
        rsum += __shfl_xor(rsum, 32, 64);
        l_i += rsum;

        // ---- O += P @ V, P fully in-register (k-slot permutation pi) ----
        // k-slot (quad,j) <-> t = sg*32 + quad*4 + (j&3) + (j>>2)*16 (bijective
        // over 32 slots). A-side: pf[j] = xv[2sg+(j>>2)][j&3] -- lane-local.
        // B-side: vf = two b64 reads of Vt[dv] at t-runs {sg*32+quad*4,
        // sg*32+16+quad*4}; each 4-run lies inside one 8-elem swizzle chunk.
#pragma unroll
        for (int sg = 0; sg < 2; sg++) {
            alignas(16) bf16 pfa[8];
#pragma unroll
            for (int j = 0; j < 4; j++) {
                pfa[j]     = (bf16)xv[2 * sg][j];
                pfa[j + 4] = (bf16)xv[2 * sg + 1][j];
            }
            bf16x8 pf = *(const bf16x8*)pfa;
            const int cLo = sg * 4 + (quad >> 1);
            const int cHi = cLo + 2;
            const int off = (quad & 1) * 4;
#pragma unroll
            for (int nj = 0; nj < 8; nj++) {
                int dv = nj * 16 + l15;
                int d7 = dv & 7;
                alignas(16) bf16 vfa[8];
                *(uint2*)&vfa[0] = *(const uint2*)&Vt[dv * 64 + ((cLo ^ d7) * 8) + off];
                *(uint2*)&vfa[4] = *(const uint2*)&Vt[dv * 64 + ((cHi ^ d7) * 8) + off];
                bf16x8 vf = *(const bf16x8*)vfa;
                acc_o[nj] = mfma16(pf, vf, acc_o[nj]);
            }
        }
    }
    // epilogue: l for acc rows fetched from lane l15 = quad*4+r
    float lr[4];
#pragma unroll
    for (int r = 0; r < 4; r++) lr[r] = __shfl(l_i, quad * 4 + r, 64);
#pragma unroll
    for (int nj = 0; nj < 8; nj++) {
        int col = h * 128 + nj * 16 + l15;
#pragma unroll
        for (int r = 0; r < 4; r++) {
            float v = acc_o[nj][r] / lr[r];
            Og[((size_t)(b * S_) + s_base + r) * 2048 + col] = (bf16)v;
        }
    }
}

// ---------------------------------------------------------------------------
extern "C" void kernel_launch(void* const* d_in, const int* in_sizes, int n_in,
                              void* d_out, int out_size, void* d_ws, size_t ws_size,
                              hipStream_t stream) {
    const float* x        = (const float*)d_in[0];   // (4096, 2048) fp32
    const float* wq_a     = (const float*)d_in[1];   // (1536, 2048) fp32
    const float* q_norm_w = (const float*)d_in[2];   // (1536,) fp32
    const float* wq_b     = (const float*)d_in[3];   // (2048, 1536) fp32
    const float* wkv_a    = (const float*)d_in[4];   // (1088, 2048) fp32
    const float* kv_norm_w= (const float*)d_in[5];   // (1024,) fp32
    const float* wkv_b    = (const float*)d_in[6];   // (3072, 1024) fp32
    const float* wo       = (const float*)d_in[7];   // (2048, 2048) fp32
    const float* fcos     = (const float*)d_in[9];   // (2048, 32) fp32
    const float* fsin     = (const float*)d_in[10];  // (2048, 32) fp32
    float* out = (float*)d_out;                      // (4096, 2048) fp32

    char* ws = (char*)d_ws;
    bf16* kv2   = (bf16*)(ws);                  // 25.2MB
    bf16* kpe   = (bf16*)(ws + 25165824);       // 0.5MB
    bf16* cq    = (bf16*)(ws + 25690112);       // 21.5MB combined kvb|qa; attno later
    bf16* xb    = (bf16*)(ws + 47185920);       // 16.8MB
    bf16* wslot = (bf16*)(ws + 63963136);       // 11.0MB weight slot
    bf16* attno = cq;                           // reuse after q_b gemm
    bf16* qbuf  = (bf16*)d_out;                 // bf16 in d_out

    dim3 blk(256), blk512(512);
    // ---- convert x once ----
    f2b<<<8192, blk, 0, stream>>>(x, xb, 2097152);
    // ---- fused A-projections: cq = xb @ [wkv_a; wq_a]^T (N=2624) ----
    f2b<<<2176, blk, 0, stream>>>(wkv_a, wslot, 557056);              // rows 0-1087
    f2b<<<3072, blk, 0, stream>>>(wq_a, wslot + 1088 * 2048, 786432); // rows 1088-2623
    // ragged N=2624: staging reads wslot rows up to 2687 (junk ok, cols>=2624
    // never stored); 2688*2048*2 = 11.01MB fits wslot region.
    gemm_bt<false><<<dim3(32, 21), blk512, 0, stream>>>(xb, wslot, cq, 4096, 2624, 2048, 2048, 2048, 2624);
    // ---- KV path ----
    rope_k<<<512, blk, 0, stream>>>(cq, kpe, fcos, fsin);
    rmsnorm_ip<<<4096, blk, 0, stream>>>(cq, kv_norm_w, 1024, 2624);
    f2b<<<3072, blk, 0, stream>>>(wkv_b, wslot, 786432);   // 3072*1024/4
    gemm_bt<false><<<dim3(32, 24), blk512, 0, stream>>>(cq, wslot, kv2, 4096, 3072, 1024, 2624, 1024, 3072);
    // ---- Q path (qa = cq cols 1088..2623; qbuf in d_out) ----
    rmsnorm_ip<<<4096, blk, 0, stream>>>(cq + 1088, q_norm_w, 1536, 2624);
    f2b<<<3072, blk, 0, stream>>>(wq_b, wslot, 786432);    // 2048*1536/4
    gemm_bt<false><<<dim3(32, 16), blk512, 0, stream>>>(cq + 1088, wslot, qbuf, 4096, 2048, 1536, 2624, 1536, 2048);
    rope_q<<<8192, blk, 0, stream>>>(qbuf, fcos, fsin);
    // ---- attention (cq region becomes attno) ----
    attn_kernel<<<dim3(16, 16, 2), dim3(512), 0, stream>>>(qbuf, kv2, kpe, attno);
    // ---- output projection (fp32 store) ----
    f2b<<<4096, blk, 0, stream>>>(wo, wslot, 1048576);     // 2048*2048/4
    gemm_bt<true><<<dim3(32, 16), blk512, 0, stream>>>(attno, wslot, out, 4096, 2048, 2048, 2048, 2048, 2048);
}